// Round 5
// baseline (532.708 us; speedup 1.0000x reference)
//
#include <hip/hip_runtime.h>

// N=4, Cin=512, C=D=256, S=H*W=16384
// prep   : split coarse -> q hi/lo bf16 (RTNE) | fold BN into w1 -> hi/lo
// conv   : k = relu(BN(conv1)), NT-MFMA 3-pass hi/lo. BARRIER-FREE: A (w1) frags and
//          B (feat fp32) elements loaded directly from global (64B-dense patterns, L2
//          absorbs the 2x in-block redundancy); in-register truncation hi/lo split.
// energy : Ep[64 splits] = q.k^T, 3-pass hi/lo, BARRIER-FREE direct dwordx4 frag loads.
// softmax: att = softmax(-sum Ep) over c (max-shift cancels)
// m2h    : M2[o,d] = w2 @ att^T -> bf16
// final  : out = M2 @ q + b2, 1-pass, barrier-free, B = coarse fp32 + RTNE cvt.
// Precision: hi/lo bf16 split keeps |dE|~1e-3; trunc-split residual terms ~2^-16 rel.

#define S_DIM 16384
#define C_DIM 256
#define CIN 512

typedef unsigned short u16;
typedef __attribute__((ext_vector_type(8))) short bf16x8;
typedef __attribute__((ext_vector_type(4))) float f32x4;

__device__ __forceinline__ u16 f2bf(float x) {  // RTNE
    unsigned u = __float_as_uint(x);
    u += 0x7fff + ((u >> 16) & 1);
    return (u16)(u >> 16);
}
__device__ __forceinline__ float bf2f(u16 h) {
    return __uint_as_float(((unsigned)h) << 16);
}

// ================= prep: split coarse -> q hi/lo | fold w1 =================
__global__ __launch_bounds__(256) void prep_kernel(
    const float* __restrict__ coarse, const float* __restrict__ w1,
    const float* __restrict__ gamma, const float* __restrict__ beta,
    const float* __restrict__ mean, const float* __restrict__ var,
    u16* __restrict__ qhi, u16* __restrict__ qlo,
    u16* __restrict__ w1hi, u16* __restrict__ w1lo, float* __restrict__ b1) {
    int b = blockIdx.x;
    int t = threadIdx.x;
    if (b < 4096) {
        size_t i = (size_t)b * 256 + t;
        for (size_t c = i; c < 4194304u; c += 1048576u) {
            float4 v = ((const float4*)coarse)[c];
            float vv[4] = {v.x, v.y, v.z, v.w};
            u16 h[4], l[4];
#pragma unroll
            for (int j = 0; j < 4; ++j) {
                h[j] = f2bf(vv[j]);
                l[j] = f2bf(vv[j] - bf2f(h[j]));
            }
            *(uint2*)&qhi[c * 4] = *(uint2*)h;
            *(uint2*)&qlo[c * 4] = *(uint2*)l;
        }
    } else {
        int o = (b - 4096) * 16 + (t >> 4);
        int lane16 = t & 15;
        float sc = gamma[o] * rsqrtf(var[o] + 1e-5f);
        for (int i = lane16; i < CIN; i += 16) {
            float v = w1[o * CIN + i] * sc;
            u16 h = f2bf(v);
            w1hi[o * CIN + i] = h;
            w1lo[o * CIN + i] = f2bf(v - bf2f(h));
        }
        if (lane16 == 0) b1[o] = beta[o] - mean[o] * sc;
    }
}

// ================= conv: k = relu(BN(w1 @ feat)), 3-pass, barrier-free =================
// grid (128 s-tiles, 2 m-tiles, 4 batch), 256 thr = 4 waves (2x2 of 64x64).
__global__ __launch_bounds__(256) void conv_kernel(
    const u16* __restrict__ w1hi, const u16* __restrict__ w1lo,
    const float* __restrict__ feat, const float* __restrict__ b1,
    u16* __restrict__ khi, u16* __restrict__ klo) {
    int s0 = blockIdx.x * 128;
    int m0 = blockIdx.y * 128;
    int bz = blockIdx.z;
    int tid = threadIdx.x, wave = tid >> 6, lane = tid & 63;
    int quad = lane >> 4, l15 = lane & 15;
    int wm = wave >> 1, wn = wave & 1;

    // A frag rows: m = m0 + wm*64 + mt*16 + l15, k = kb + quad*8 + j  (64B-dense lines)
    const u16* aH = w1hi + (size_t)(m0 + wm * 64 + l15) * CIN + quad * 8;
    const u16* aL = w1lo + (size_t)(m0 + wm * 64 + l15) * CIN + quad * 8;
    // B elems: feat[(kb+quad*8+j)*S + s0 + wn*64 + nt*16 + l15]  (16-lane 64B runs)
    const float* fB = feat + (size_t)bz * ((size_t)CIN * S_DIM) +
                      (size_t)(quad * 8) * S_DIM + s0 + wn * 64 + l15;

    f32x4 zero = {0.f, 0.f, 0.f, 0.f};
    f32x4 acc[4][4];
#pragma unroll
    for (int i = 0; i < 4; ++i)
#pragma unroll
        for (int j = 0; j < 4; ++j) acc[i][j] = zero;

    for (int kb = 0; kb < CIN; kb += 32) {
        bf16x8 a_h[4], a_l[4];
#pragma unroll
        for (int mt = 0; mt < 4; ++mt) {
            a_h[mt] = *(const bf16x8*)&aH[(size_t)(mt * 16) * CIN + kb];
            a_l[mt] = *(const bf16x8*)&aL[(size_t)(mt * 16) * CIN + kb];
        }
        const float* fk = fB + (size_t)kb * S_DIM;
        bf16x8 b_h[4], b_l[4];
#pragma unroll
        for (int nt = 0; nt < 4; ++nt) {
            union { u16 u[8]; bf16x8 v; } th, tl;
#pragma unroll
            for (int j = 0; j < 8; ++j) {
                float f = fk[(size_t)j * S_DIM + nt * 16];
                unsigned u = __float_as_uint(f);
                u16 h = (u16)(u >> 16);              // truncation split: residual is
                th.u[j] = h;                          // captured exactly by lo
                tl.u[j] = (u16)(__float_as_uint(f - bf2f(h)) >> 16);
            }
            b_h[nt] = th.v;
            b_l[nt] = tl.v;
        }
#pragma unroll
        for (int mt = 0; mt < 4; ++mt)
#pragma unroll
            for (int nt = 0; nt < 4; ++nt) {
                acc[mt][nt] = __builtin_amdgcn_mfma_f32_16x16x32_bf16(a_h[mt], b_h[nt], acc[mt][nt], 0, 0, 0);
                acc[mt][nt] = __builtin_amdgcn_mfma_f32_16x16x32_bf16(a_h[mt], b_l[nt], acc[mt][nt], 0, 0, 0);
                acc[mt][nt] = __builtin_amdgcn_mfma_f32_16x16x32_bf16(a_l[mt], b_h[nt], acc[mt][nt], 0, 0, 0);
            }
    }

#pragma unroll
    for (int mt = 0; mt < 4; ++mt)
#pragma unroll
        for (int r = 0; r < 4; ++r) {
            int row = m0 + wm * 64 + mt * 16 + quad * 4 + r;
            float bi = b1[row];
#pragma unroll
            for (int nt = 0; nt < 4; ++nt) {
                int cc = s0 + wn * 64 + nt * 16 + l15;
                float v = fmaxf(acc[mt][nt][r] + bi, 0.f);
                u16 h = f2bf(v);
                size_t o = (size_t)bz * 4194304 + (size_t)row * S_DIM + cc;
                khi[o] = h;
                klo[o] = f2bf(v - bf2f(h));
            }
        }
}

// ================= energy: Ep[split] = q.k^T, 3-pass, barrier-free =================
// grid (64 splits, 4 tile-combos, 4 batch)
__global__ __launch_bounds__(256) void energy_kernel(
    const u16* __restrict__ qhi, const u16* __restrict__ qlo,
    const u16* __restrict__ khi, const u16* __restrict__ klo,
    float* __restrict__ Ep) {
    int kBeg = blockIdx.x * 256;
    int m0 = (blockIdx.y >> 1) * 128;
    int n0 = (blockIdx.y & 1) * 128;
    int bz = blockIdx.z;
    int tid = threadIdx.x, wave = tid >> 6, lane = tid & 63;
    int quad = lane >> 4, l15 = lane & 15;
    int wm = wave >> 1, wn = wave & 1;

    size_t bo = (size_t)bz * 4194304;
    const u16* aH = qhi + bo + (size_t)(m0 + wm * 64 + l15) * S_DIM + kBeg + quad * 8;
    const u16* aL = qlo + bo + (size_t)(m0 + wm * 64 + l15) * S_DIM + kBeg + quad * 8;
    const u16* bH = khi + bo + (size_t)(n0 + wn * 64 + l15) * S_DIM + kBeg + quad * 8;
    const u16* bL = klo + bo + (size_t)(n0 + wn * 64 + l15) * S_DIM + kBeg + quad * 8;

    f32x4 zero = {0.f, 0.f, 0.f, 0.f};
    f32x4 acc[4][4];
#pragma unroll
    for (int i = 0; i < 4; ++i)
#pragma unroll
        for (int j = 0; j < 4; ++j) acc[i][j] = zero;

    for (int kb = 0; kb < 256; kb += 32) {
        bf16x8 a_h[4], a_l[4], b_h[4], b_l[4];
#pragma unroll
        for (int t = 0; t < 4; ++t) {
            a_h[t] = *(const bf16x8*)&aH[(size_t)(t * 16) * S_DIM + kb];
            a_l[t] = *(const bf16x8*)&aL[(size_t)(t * 16) * S_DIM + kb];
            b_h[t] = *(const bf16x8*)&bH[(size_t)(t * 16) * S_DIM + kb];
            b_l[t] = *(const bf16x8*)&bL[(size_t)(t * 16) * S_DIM + kb];
        }
#pragma unroll
        for (int mt = 0; mt < 4; ++mt)
#pragma unroll
            for (int nt = 0; nt < 4; ++nt) {
                acc[mt][nt] = __builtin_amdgcn_mfma_f32_16x16x32_bf16(a_h[mt], b_h[nt], acc[mt][nt], 0, 0, 0);
                acc[mt][nt] = __builtin_amdgcn_mfma_f32_16x16x32_bf16(a_h[mt], b_l[nt], acc[mt][nt], 0, 0, 0);
                acc[mt][nt] = __builtin_amdgcn_mfma_f32_16x16x32_bf16(a_l[mt], b_h[nt], acc[mt][nt], 0, 0, 0);
            }
    }

    float* Ce = Ep + ((size_t)(blockIdx.x * 4 + bz)) * 65536;
#pragma unroll
    for (int mt = 0; mt < 4; ++mt)
#pragma unroll
        for (int r = 0; r < 4; ++r) {
            int row = m0 + wm * 64 + mt * 16 + quad * 4 + r;
#pragma unroll
            for (int nt = 0; nt < 4; ++nt) {
                int cc = n0 + wn * 64 + nt * 16 + l15;
                Ce[(size_t)row * C_DIM + cc] = acc[mt][nt][r];
            }
        }
}

// ================= softmax(-sum Ep) over c =================
__global__ __launch_bounds__(256) void softmax_kernel(const float* __restrict__ Ep,
                                                      float* __restrict__ att) {
    __shared__ float red[4], red2[4];
    int b = blockIdx.x;  // n*256+d
    int t = threadIdx.x;
    const float* p = Ep + (size_t)b * 256 + t;
    float v = 0.f;
#pragma unroll 8
    for (int s = 0; s < 64; ++s) v += p[(size_t)s * 262144];
    float m = v;
#pragma unroll
    for (int o = 32; o > 0; o >>= 1) m = fminf(m, __shfl_xor(m, o, 64));
    int lane = t & 63, wid = t >> 6;
    if (lane == 0) red[wid] = m;
    __syncthreads();
    m = fminf(fminf(red[0], red[1]), fminf(red[2], red[3]));
    float e = expf(m - v);
    float s = e;
#pragma unroll
    for (int o = 32; o > 0; o >>= 1) s += __shfl_xor(s, o, 64);
    if (lane == 0) red2[wid] = s;
    __syncthreads();
    s = red2[0] + red2[1] + red2[2] + red2[3];
    att[(size_t)b * 256 + t] = e / s;
}

// ================= M2h[n,o,d] = bf16( sum_c w2[o,c]*att[n,d,c] ) =================
__global__ __launch_bounds__(256) void m2h_kernel(const float* __restrict__ w2,
                                                  const float* __restrict__ att,
                                                  u16* __restrict__ M2h) {
    int t = blockIdx.x * 256 + threadIdx.x;
    int d = t & 255, o = (t >> 8) & 255, n = t >> 16;
    const float4* wr = (const float4*)(w2 + (size_t)o * C_DIM);
    const float4* ar = (const float4*)(att + ((size_t)n * C_DIM + d) * C_DIM);
    float s = 0.0f;
#pragma unroll 4
    for (int c4 = 0; c4 < 64; ++c4) {
        float4 w = wr[c4];
        float4 a = ar[c4];
        s += w.x * a.x + w.y * a.y + w.z * a.z + w.w * a.w;
    }
    M2h[((size_t)n * C_DIM + o) * C_DIM + d] = f2bf(s);
}

// ================= final: out = M2 @ q + b2, 1-pass, barrier-free =================
__global__ __launch_bounds__(256) void final_kernel(
    const u16* __restrict__ M2h, const float* __restrict__ coarse,
    const float* __restrict__ b2, float* __restrict__ out) {
    int s0 = blockIdx.x * 128;
    int m0 = blockIdx.y * 128;
    int bz = blockIdx.z;
    int tid = threadIdx.x, wave = tid >> 6, lane = tid & 63;
    int quad = lane >> 4, l15 = lane & 15;
    int wm = wave >> 1, wn = wave & 1;

    const u16* aH = M2h + (size_t)bz * 65536 + (size_t)(m0 + wm * 64 + l15) * C_DIM + quad * 8;
    const float* fB = coarse + (size_t)bz * 4194304 +
                      (size_t)(quad * 8) * S_DIM + s0 + wn * 64 + l15;

    f32x4 zero = {0.f, 0.f, 0.f, 0.f};
    f32x4 acc[4][4];
#pragma unroll
    for (int i = 0; i < 4; ++i)
#pragma unroll
        for (int j = 0; j < 4; ++j) acc[i][j] = zero;

    for (int kb = 0; kb < C_DIM; kb += 32) {
        bf16x8 a_h[4];
#pragma unroll
        for (int mt = 0; mt < 4; ++mt)
            a_h[mt] = *(const bf16x8*)&aH[(size_t)(mt * 16) * C_DIM + kb];
        const float* fk = fB + (size_t)kb * S_DIM;
        bf16x8 b_h[4];
#pragma unroll
        for (int nt = 0; nt < 4; ++nt) {
            union { u16 u[8]; bf16x8 v; } th;
#pragma unroll
            for (int j = 0; j < 8; ++j) th.u[j] = f2bf(fk[(size_t)j * S_DIM + nt * 16]);
            b_h[nt] = th.v;
        }
#pragma unroll
        for (int mt = 0; mt < 4; ++mt)
#pragma unroll
            for (int nt = 0; nt < 4; ++nt)
                acc[mt][nt] = __builtin_amdgcn_mfma_f32_16x16x32_bf16(a_h[mt], b_h[nt], acc[mt][nt], 0, 0, 0);
    }

#pragma unroll
    for (int mt = 0; mt < 4; ++mt)
#pragma unroll
        for (int r = 0; r < 4; ++r) {
            int row = m0 + wm * 64 + mt * 16 + quad * 4 + r;
            float bi = b2[row];
#pragma unroll
            for (int nt = 0; nt < 4; ++nt) {
                int cc = s0 + wn * 64 + nt * 16 + l15;
                out[(size_t)bz * 4194304 + (size_t)row * S_DIM + cc] = acc[mt][nt][r] + bi;
            }
        }
}

extern "C" void kernel_launch(void* const* d_in, const int* in_sizes, int n_in,
                              void* d_out, int out_size, void* d_ws, size_t ws_size,
                              hipStream_t stream) {
    const float* feat   = (const float*)d_in[0];
    const float* coarse = (const float*)d_in[1];
    const float* w1     = (const float*)d_in[2];
    const float* gamma  = (const float*)d_in[3];
    const float* beta   = (const float*)d_in[4];
    const float* mean   = (const float*)d_in[5];
    const float* var    = (const float*)d_in[6];
    const float* w2     = (const float*)d_in[7];
    const float* b2     = (const float*)d_in[8];
    float* out = (float*)d_out;

    char* base = (char*)d_ws;  // ~204 MB
    u16* qhi   = (u16*)(base);                   // [4][256][16384]
    u16* qlo   = (u16*)(base + 33554432);
    u16* khi   = (u16*)(base + 67108864);        // [4][256][16384]
    u16* klo   = (u16*)(base + 100663296);
    float* Ep  = (float*)(base + 134217728);     // [64][4][256][256] = 67 MB
    float* att = (float*)(base + 201326592);     // [4][256][256]
    u16* M2h   = (u16*)(base + 202375168);
    u16* w1hi  = (u16*)(base + 202899456);
    u16* w1lo  = (u16*)(base + 203161600);
    float* b1  = (float*)(base + 203423744);

    prep_kernel<<<4112, 256, 0, stream>>>(coarse, w1, gamma, beta, mean, var,
                                          qhi, qlo, w1hi, w1lo, b1);

    conv_kernel<<<dim3(128, 2, 4), 256, 0, stream>>>(w1hi, w1lo, feat, b1, khi, klo);

    energy_kernel<<<dim3(64, 4, 4), 256, 0, stream>>>(qhi, qlo, khi, klo, Ep);

    softmax_kernel<<<1024, 256, 0, stream>>>(Ep, att);

    m2h_kernel<<<1024, 256, 0, stream>>>(w2, att, M2h);

    final_kernel<<<dim3(128, 2, 4), 256, 0, stream>>>(M2h, coarse, b2, out);
}

// Round 6
// 468.440 us; speedup vs baseline: 1.1372x; 1.1372x over previous
//
#include <hip/hip_runtime.h>

// N=4, Cin=512, C=D=256, S=H*W=16384
// prep   : split coarse -> q hi/lo bf16 | fold BN into w1 -> hi/lo
// conv   : k = relu(BN(conv1)), 3-pass hi/lo. A = w1 direct-global dwordx4 (L2-hot);
//          B = feat fp32 staged to LDS via width-16 global_load_lds, PING-PONG buffer,
//          ONE barrier/step (stage t+1 overlaps compute t); column gather + trunc split.
// energy : Ep[64 splits] = q.k^T, 3-pass hi/lo, FRAG-MAJOR LDS (conflict-free b128).
// softmax: att = softmax(-sum Ep) over c (max-shift cancels)
// m2h    : M2[o,d] = w2 @ att^T -> bf16
// final  : out = M2 @ q + b2, 1-pass; A = M2h direct-global; B = coarse via ping-pong LDS.
// Precision: hi/lo bf16 split keeps |dE|~1e-3 (plain bf16 would flip softmax near-ties).

#define S_DIM 16384
#define C_DIM 256
#define CIN 512

typedef unsigned short u16;
typedef __attribute__((ext_vector_type(8))) short bf16x8;
typedef __attribute__((ext_vector_type(4))) float f32x4;

__device__ __forceinline__ u16 f2bf(float x) {  // RTNE
    unsigned u = __float_as_uint(x);
    u += 0x7fff + ((u >> 16) & 1);
    return (u16)(u >> 16);
}
__device__ __forceinline__ float bf2f(u16 h) {
    return __uint_as_float(((unsigned)h) << 16);
}
__device__ __forceinline__ void gld16(const void* g, void* l) {
    __builtin_amdgcn_global_load_lds((const __attribute__((address_space(1))) void*)g,
                                     (__attribute__((address_space(3))) void*)l, 16, 0, 0);
}

// ================= prep: split coarse -> q hi/lo | fold w1 =================
__global__ __launch_bounds__(256) void prep_kernel(
    const float* __restrict__ coarse, const float* __restrict__ w1,
    const float* __restrict__ gamma, const float* __restrict__ beta,
    const float* __restrict__ mean, const float* __restrict__ var,
    u16* __restrict__ qhi, u16* __restrict__ qlo,
    u16* __restrict__ w1hi, u16* __restrict__ w1lo, float* __restrict__ b1) {
    int b = blockIdx.x;
    int t = threadIdx.x;
    if (b < 4096) {
        size_t i = (size_t)b * 256 + t;
        for (size_t c = i; c < 4194304u; c += 1048576u) {
            float4 v = ((const float4*)coarse)[c];
            float vv[4] = {v.x, v.y, v.z, v.w};
            u16 h[4], l[4];
#pragma unroll
            for (int j = 0; j < 4; ++j) {
                h[j] = f2bf(vv[j]);
                l[j] = f2bf(vv[j] - bf2f(h[j]));
            }
            *(uint2*)&qhi[c * 4] = *(uint2*)h;
            *(uint2*)&qlo[c * 4] = *(uint2*)l;
        }
    } else {
        int o = (b - 4096) * 16 + (t >> 4);
        int lane16 = t & 15;
        float sc = gamma[o] * rsqrtf(var[o] + 1e-5f);
        for (int i = lane16; i < CIN; i += 16) {
            float v = w1[o * CIN + i] * sc;
            u16 h = f2bf(v);
            w1hi[o * CIN + i] = h;
            w1lo[o * CIN + i] = f2bf(v - bf2f(h));
        }
        if (lane16 == 0) b1[o] = beta[o] - mean[o] * sc;
    }
}

// ================= conv: k = relu(BN(w1 @ feat)), 3-pass, ping-pong =================
// grid (128 s-tiles, 2 m-tiles, 4 batch), 256 thr = 4 waves (2x2 of 64x64).
__global__ __launch_bounds__(256) void conv_kernel(
    const u16* __restrict__ w1hi, const u16* __restrict__ w1lo,
    const float* __restrict__ feat, const float* __restrict__ b1,
    u16* __restrict__ khi, u16* __restrict__ klo) {
    __shared__ float Bf[2][32 * 128];  // 2 x 16 KB ping-pong, rows contiguous
    int s0 = blockIdx.x * 128;
    int m0 = blockIdx.y * 128;
    int bz = blockIdx.z;
    int tid = threadIdx.x, wave = tid >> 6, lane = tid & 63;
    int quad = lane >> 4, l15 = lane & 15;
    int wm = wave >> 1, wn = wave & 1;

    // A frags direct from global (w1 is 256 KB -> L2-hot)
    const u16* aH = w1hi + (size_t)(m0 + wm * 64 + l15) * CIN + quad * 8;
    const u16* aL = w1lo + (size_t)(m0 + wm * 64 + l15) * CIN + quad * 8;

    // B staging: 4 slots/thread; slot sl = wave*256 + p*64 + lane; row=sl>>5, grp=sl&31
    const float* fb = feat + (size_t)bz * ((size_t)CIN * S_DIM) + s0;
    int srow[4], sgrp[4];
#pragma unroll
    for (int p = 0; p < 4; ++p) {
        int sl = wave * 256 + p * 64 + lane;
        srow[p] = sl >> 5;
        sgrp[p] = (sl & 31) * 4;
    }

    f32x4 zero = {0.f, 0.f, 0.f, 0.f};
    f32x4 acc[4][4];
#pragma unroll
    for (int i = 0; i < 4; ++i)
#pragma unroll
        for (int j = 0; j < 4; ++j) acc[i][j] = zero;

    // stage step 0 into buf 0
#pragma unroll
    for (int p = 0; p < 4; ++p)
        gld16(fb + (size_t)srow[p] * S_DIM + sgrp[p], &Bf[0][wave * 1024 + p * 256 + lane * 4]);

    for (int it = 0; it < 16; ++it) {
        int kb = it * 32;
        __syncthreads();  // drains stage(it) [vmcnt], syncs gathers of it-1

        // A-frag loads FIRST (so vmcnt waits for them don't drain next staging)
        bf16x8 a_h[4], a_l[4];
#pragma unroll
        for (int mt = 0; mt < 4; ++mt) {
            a_h[mt] = *(const bf16x8*)&aH[(size_t)(mt * 16) * CIN + kb];
            a_l[mt] = *(const bf16x8*)&aL[(size_t)(mt * 16) * CIN + kb];
        }
        // stage step it+1 into other buffer (overlaps compute below)
        if (it < 15) {
            const float* fn = fb + (size_t)(kb + 32) * S_DIM;
            float* dst = &Bf[(it + 1) & 1][wave * 1024 + lane * 4];
#pragma unroll
            for (int p = 0; p < 4; ++p)
                gld16(fn + (size_t)srow[p] * S_DIM + sgrp[p], dst + p * 256);
        }
        // gather + trunc-split cvt from current buffer
        const float* B = Bf[it & 1];
        bf16x8 b_h[4], b_l[4];
#pragma unroll
        for (int nt = 0; nt < 4; ++nt) {
            int n = wn * 64 + nt * 16 + l15;
            union { u16 u[8]; bf16x8 v; } th, tl;
#pragma unroll
            for (int j = 0; j < 8; ++j) {
                float f = B[(quad * 8 + j) * 128 + n];
                u16 h = (u16)(__float_as_uint(f) >> 16);
                th.u[j] = h;
                tl.u[j] = (u16)(__float_as_uint(f - bf2f(h)) >> 16);
            }
            b_h[nt] = th.v;
            b_l[nt] = tl.v;
        }
#pragma unroll
        for (int mt = 0; mt < 4; ++mt)
#pragma unroll
            for (int nt = 0; nt < 4; ++nt) {
                acc[mt][nt] = __builtin_amdgcn_mfma_f32_16x16x32_bf16(a_h[mt], b_h[nt], acc[mt][nt], 0, 0, 0);
                acc[mt][nt] = __builtin_amdgcn_mfma_f32_16x16x32_bf16(a_h[mt], b_l[nt], acc[mt][nt], 0, 0, 0);
                acc[mt][nt] = __builtin_amdgcn_mfma_f32_16x16x32_bf16(a_l[mt], b_h[nt], acc[mt][nt], 0, 0, 0);
            }
    }

#pragma unroll
    for (int mt = 0; mt < 4; ++mt)
#pragma unroll
        for (int r = 0; r < 4; ++r) {
            int row = m0 + wm * 64 + mt * 16 + quad * 4 + r;
            float bi = b1[row];
#pragma unroll
            for (int nt = 0; nt < 4; ++nt) {
                int cc = s0 + wn * 64 + nt * 16 + l15;
                float v = fmaxf(acc[mt][nt][r] + bi, 0.f);
                u16 h = f2bf(v);
                size_t o = (size_t)bz * 4194304 + (size_t)row * S_DIM + cc;
                khi[o] = h;
                klo[o] = f2bf(v - bf2f(h));
            }
        }
}

// ================= energy: Ep[split] = q.k^T, 3-pass, frag-major LDS =================
// grid (64 splits, 4 tile-combos, 4 batch). Conflict-free b128 frag reads.
__global__ __launch_bounds__(256) void energy_kernel(
    const u16* __restrict__ qhi, const u16* __restrict__ qlo,
    const u16* __restrict__ khi, const u16* __restrict__ klo,
    float* __restrict__ Ep) {
    __shared__ u16 AhS[4096], AlS[4096], BhS[4096], BlS[4096];  // 8 KB each
    int kBeg = blockIdx.x * 256;
    int m0 = (blockIdx.y >> 1) * 128;
    int n0 = (blockIdx.y & 1) * 128;
    int bz = blockIdx.z;
    int tid = threadIdx.x, wave = tid >> 6, lane = tid & 63;
    int quad = lane >> 4, l15 = lane & 15;
    int wm = wave >> 1, wn = wave & 1;

    // staging slots: thread covers sl0 = wave*128+lane, sl1 = sl0+64 for each buffer.
    // slot sl -> sub = sl>>6 (m-subtile), q=(sl>>4)&3, l15s = sl&15; row = sub*16+l15s.
    size_t bo = (size_t)bz * 4194304;
    int sl0 = wave * 128 + lane, sl1 = sl0 + 64;
    int row0 = (sl0 >> 6) * 16 + (sl0 & 15), k0 = ((sl0 >> 4) & 3) * 8;
    int row1 = (sl1 >> 6) * 16 + (sl1 & 15), k1 = ((sl1 >> 4) & 3) * 8;
    const u16* gA0h = qhi + bo + (size_t)(m0 + row0) * S_DIM + kBeg + k0;
    const u16* gA1h = qhi + bo + (size_t)(m0 + row1) * S_DIM + kBeg + k1;
    const u16* gA0l = qlo + bo + (size_t)(m0 + row0) * S_DIM + kBeg + k0;
    const u16* gA1l = qlo + bo + (size_t)(m0 + row1) * S_DIM + kBeg + k1;
    const u16* gB0h = khi + bo + (size_t)(n0 + row0) * S_DIM + kBeg + k0;
    const u16* gB1h = khi + bo + (size_t)(n0 + row1) * S_DIM + kBeg + k1;
    const u16* gB0l = klo + bo + (size_t)(n0 + row0) * S_DIM + kBeg + k0;
    const u16* gB1l = klo + bo + (size_t)(n0 + row1) * S_DIM + kBeg + k1;

    f32x4 zero = {0.f, 0.f, 0.f, 0.f};
    f32x4 acc[4][4];
#pragma unroll
    for (int i = 0; i < 4; ++i)
#pragma unroll
        for (int j = 0; j < 4; ++j) acc[i][j] = zero;

    for (int kb = 0; kb < 256; kb += 32) {
        __syncthreads();
        gld16(gA0h + kb, AhS + sl0 * 8);
        gld16(gA1h + kb, AhS + sl1 * 8);
        gld16(gA0l + kb, AlS + sl0 * 8);
        gld16(gA1l + kb, AlS + sl1 * 8);
        gld16(gB0h + kb, BhS + sl0 * 8);
        gld16(gB1h + kb, BhS + sl1 * 8);
        gld16(gB0l + kb, BlS + sl0 * 8);
        gld16(gB1l + kb, BlS + sl1 * 8);
        __syncthreads();

        bf16x8 a_h[4], a_l[4], b_h[4], b_l[4];
#pragma unroll
        for (int t = 0; t < 4; ++t) {
            a_h[t] = *(const bf16x8*)&AhS[((wm * 4 + t) * 64 + lane) * 8];
            a_l[t] = *(const bf16x8*)&AlS[((wm * 4 + t) * 64 + lane) * 8];
            b_h[t] = *(const bf16x8*)&BhS[((wn * 4 + t) * 64 + lane) * 8];
            b_l[t] = *(const bf16x8*)&BlS[((wn * 4 + t) * 64 + lane) * 8];
        }
#pragma unroll
        for (int mt = 0; mt < 4; ++mt)
#pragma unroll
            for (int nt = 0; nt < 4; ++nt) {
                acc[mt][nt] = __builtin_amdgcn_mfma_f32_16x16x32_bf16(a_h[mt], b_h[nt], acc[mt][nt], 0, 0, 0);
                acc[mt][nt] = __builtin_amdgcn_mfma_f32_16x16x32_bf16(a_h[mt], b_l[nt], acc[mt][nt], 0, 0, 0);
                acc[mt][nt] = __builtin_amdgcn_mfma_f32_16x16x32_bf16(a_l[mt], b_h[nt], acc[mt][nt], 0, 0, 0);
            }
    }

    float* Ce = Ep + ((size_t)(blockIdx.x * 4 + bz)) * 65536;
#pragma unroll
    for (int mt = 0; mt < 4; ++mt)
#pragma unroll
        for (int r = 0; r < 4; ++r) {
            int row = m0 + wm * 64 + mt * 16 + quad * 4 + r;
#pragma unroll
            for (int nt = 0; nt < 4; ++nt) {
                int cc = n0 + wn * 64 + nt * 16 + l15;
                Ce[(size_t)row * C_DIM + cc] = acc[mt][nt][r];
            }
        }
}

// ================= softmax(-sum Ep) over c =================
__global__ __launch_bounds__(256) void softmax_kernel(const float* __restrict__ Ep,
                                                      float* __restrict__ att) {
    __shared__ float red[4], red2[4];
    int b = blockIdx.x;  // n*256+d
    int t = threadIdx.x;
    const float* p = Ep + (size_t)b * 256 + t;
    float v = 0.f;
#pragma unroll 8
    for (int s = 0; s < 64; ++s) v += p[(size_t)s * 262144];
    float m = v;
#pragma unroll
    for (int o = 32; o > 0; o >>= 1) m = fminf(m, __shfl_xor(m, o, 64));
    int lane = t & 63, wid = t >> 6;
    if (lane == 0) red[wid] = m;
    __syncthreads();
    m = fminf(fminf(red[0], red[1]), fminf(red[2], red[3]));
    float e = expf(m - v);
    float s = e;
#pragma unroll
    for (int o = 32; o > 0; o >>= 1) s += __shfl_xor(s, o, 64);
    if (lane == 0) red2[wid] = s;
    __syncthreads();
    s = red2[0] + red2[1] + red2[2] + red2[3];
    att[(size_t)b * 256 + t] = e / s;
}

// ================= M2h[n,o,d] = bf16( sum_c w2[o,c]*att[n,d,c] ) =================
__global__ __launch_bounds__(256) void m2h_kernel(const float* __restrict__ w2,
                                                  const float* __restrict__ att,
                                                  u16* __restrict__ M2h) {
    int t = blockIdx.x * 256 + threadIdx.x;
    int d = t & 255, o = (t >> 8) & 255, n = t >> 16;
    const float4* wr = (const float4*)(w2 + (size_t)o * C_DIM);
    const float4* ar = (const float4*)(att + ((size_t)n * C_DIM + d) * C_DIM);
    float s = 0.0f;
#pragma unroll 4
    for (int c4 = 0; c4 < 64; ++c4) {
        float4 w = wr[c4];
        float4 a = ar[c4];
        s += w.x * a.x + w.y * a.y + w.z * a.z + w.w * a.w;
    }
    M2h[((size_t)n * C_DIM + o) * C_DIM + d] = f2bf(s);
}

// ================= final: out = M2 @ q + b2, 1-pass, ping-pong =================
__global__ __launch_bounds__(256) void final_kernel(
    const u16* __restrict__ M2h, const float* __restrict__ coarse,
    const float* __restrict__ b2, float* __restrict__ out) {
    __shared__ float Bf[2][32 * 128];
    int s0 = blockIdx.x * 128;
    int m0 = blockIdx.y * 128;
    int bz = blockIdx.z;
    int tid = threadIdx.x, wave = tid >> 6, lane = tid & 63;
    int quad = lane >> 4, l15 = lane & 15;
    int wm = wave >> 1, wn = wave & 1;

    const u16* aH = M2h + (size_t)bz * 65536 + (size_t)(m0 + wm * 64 + l15) * C_DIM + quad * 8;
    const float* fb = coarse + (size_t)bz * 4194304 + s0;
    int srow[4], sgrp[4];
#pragma unroll
    for (int p = 0; p < 4; ++p) {
        int sl = wave * 256 + p * 64 + lane;
        srow[p] = sl >> 5;
        sgrp[p] = (sl & 31) * 4;
    }

    f32x4 zero = {0.f, 0.f, 0.f, 0.f};
    f32x4 acc[4][4];
#pragma unroll
    for (int i = 0; i < 4; ++i)
#pragma unroll
        for (int j = 0; j < 4; ++j) acc[i][j] = zero;

#pragma unroll
    for (int p = 0; p < 4; ++p)
        gld16(fb + (size_t)srow[p] * S_DIM + sgrp[p], &Bf[0][wave * 1024 + p * 256 + lane * 4]);

    for (int it = 0; it < 8; ++it) {
        int kb = it * 32;
        __syncthreads();
        bf16x8 a_h[4];
#pragma unroll
        for (int mt = 0; mt < 4; ++mt)
            a_h[mt] = *(const bf16x8*)&aH[(size_t)(mt * 16) * C_DIM + kb];
        if (it < 7) {
            const float* fn = fb + (size_t)(kb + 32) * S_DIM;
            float* dst = &Bf[(it + 1) & 1][wave * 1024 + lane * 4];
#pragma unroll
            for (int p = 0; p < 4; ++p)
                gld16(fn + (size_t)srow[p] * S_DIM + sgrp[p], dst + p * 256);
        }
        const float* B = Bf[it & 1];
        bf16x8 b_h[4];
#pragma unroll
        for (int nt = 0; nt < 4; ++nt) {
            int n = wn * 64 + nt * 16 + l15;
            union { u16 u[8]; bf16x8 v; } th;
#pragma unroll
            for (int j = 0; j < 8; ++j) th.u[j] = f2bf(B[(quad * 8 + j) * 128 + n]);
            b_h[nt] = th.v;
        }
#pragma unroll
        for (int mt = 0; mt < 4; ++mt)
#pragma unroll
            for (int nt = 0; nt < 4; ++nt)
                acc[mt][nt] = __builtin_amdgcn_mfma_f32_16x16x32_bf16(a_h[mt], b_h[nt], acc[mt][nt], 0, 0, 0);
    }

#pragma unroll
    for (int mt = 0; mt < 4; ++mt)
#pragma unroll
        for (int r = 0; r < 4; ++r) {
            int row = m0 + wm * 64 + mt * 16 + quad * 4 + r;
            float bi = b2[row];
#pragma unroll
            for (int nt = 0; nt < 4; ++nt) {
                int cc = s0 + wn * 64 + nt * 16 + l15;
                out[(size_t)bz * 4194304 + (size_t)row * S_DIM + cc] = acc[mt][nt][r] + bi;
            }
        }
}

extern "C" void kernel_launch(void* const* d_in, const int* in_sizes, int n_in,
                              void* d_out, int out_size, void* d_ws, size_t ws_size,
                              hipStream_t stream) {
    const float* feat   = (const float*)d_in[0];
    const float* coarse = (const float*)d_in[1];
    const float* w1     = (const float*)d_in[2];
    const float* gamma  = (const float*)d_in[3];
    const float* beta   = (const float*)d_in[4];
    const float* mean   = (const float*)d_in[5];
    const float* var    = (const float*)d_in[6];
    const float* w2     = (const float*)d_in[7];
    const float* b2     = (const float*)d_in[8];
    float* out = (float*)d_out;

    char* base = (char*)d_ws;  // ~204 MB
    u16* qhi   = (u16*)(base);                   // [4][256][16384]
    u16* qlo   = (u16*)(base + 33554432);
    u16* khi   = (u16*)(base + 67108864);
    u16* klo   = (u16*)(base + 100663296);
    float* Ep  = (float*)(base + 134217728);     // [64][4][256][256] = 67 MB
    float* att = (float*)(base + 201326592);
    u16* M2h   = (u16*)(base + 202375168);
    u16* w1hi  = (u16*)(base + 202899456);
    u16* w1lo  = (u16*)(base + 203161600);
    float* b1  = (float*)(base + 203423744);

    prep_kernel<<<4112, 256, 0, stream>>>(coarse, w1, gamma, beta, mean, var,
                                          qhi, qlo, w1hi, w1lo, b1);

    conv_kernel<<<dim3(128, 2, 4), 256, 0, stream>>>(w1hi, w1lo, feat, b1, khi, klo);

    energy_kernel<<<dim3(64, 4, 4), 256, 0, stream>>>(qhi, qlo, khi, klo, Ep);

    softmax_kernel<<<1024, 256, 0, stream>>>(Ep, att);

    m2h_kernel<<<1024, 256, 0, stream>>>(w2, att, M2h);

    final_kernel<<<dim3(128, 2, 4), 256, 0, stream>>>(M2h, coarse, b2, out);
}